// Round 1
// baseline (885.076 us; speedup 1.0000x reference)
//
#include <hip/hip_runtime.h>
#include <math.h>

// Shapes (fixed)
#define B_ 4
#define S_ 256
#define N_ 32
#define H_ 256
#define NH_ 8
#define HD_ 32
#define FF_ 512
#define BN_ 128
#define M_ 32768   // BN_*S_
#define BS_ 1024   // B_*S_

// ---------------------------------------------------------------------------
// time_state[bs, h] = sess_emb[code] + reg*reg_w + reg_b + tr*tr_w + tr_b
// ---------------------------------------------------------------------------
__global__ __launch_bounds__(256)
void ts_kernel(const float* __restrict__ reg, const float* __restrict__ tr,
               const int* __restrict__ codes,
               const float* __restrict__ sess_emb,
               const float* __restrict__ reg_w, const float* __restrict__ reg_b,
               const float* __restrict__ tr_w, const float* __restrict__ tr_b,
               float* __restrict__ ts) {
  const int bs = blockIdx.x;
  const int h = threadIdx.x;
  int c = codes[bs];
  c = c < 0 ? 0 : (c > 7 ? 7 : c);
  const float r = reg[bs], t = tr[bs];
  ts[bs * H_ + h] = sess_emb[c * H_ + h] + r * reg_w[h] + reg_b[h]
                    + t * tr_w[h] + tr_b[h];
}

// ---------------------------------------------------------------------------
// Generic fp32 tiled matmul: C[M, NOUT] = epilogue(A' @ W + bias)
// AMODE: 0 = plain A[m,K]; 1 = gather sequence; 2 = gather sequence + ts
// RESMODE: 0 = none; 1 = + sequence (gather); 2 = + res[m,NOUT]
// tile 64x64, BK=32, 256 threads, 4x4 microtile.
// Token row m = bn*S + s; bn = b*32 + n; sequence is [B,S,N,H].
// ---------------------------------------------------------------------------
template<int AMODE, int RESMODE, bool GELU, int K, int NOUT>
__global__ __launch_bounds__(256)
void mm_kernel(const float* __restrict__ A, const float* __restrict__ W,
               const float* __restrict__ bias,
               const float* __restrict__ seq, const float* __restrict__ ts,
               const float* __restrict__ res,
               float* __restrict__ C, float post_scale) {
  __shared__ float As[32][68];   // [k][m], pad 68 keeps float4 alignment
  __shared__ float Ws[32][68];   // [k][n]
  const int tid = threadIdx.x;
  const int m0 = blockIdx.x * 64;
  const int n0 = blockIdx.y * 64;
  const int tm = tid >> 4, tn = tid & 15;
  float acc[4][4] = {{0.f, 0.f, 0.f, 0.f}, {0.f, 0.f, 0.f, 0.f},
                     {0.f, 0.f, 0.f, 0.f}, {0.f, 0.f, 0.f, 0.f}};

  for (int k0 = 0; k0 < K; k0 += 32) {
    // stage A tile: 64 rows x 32 cols, coalesced, store transposed
#pragma unroll
    for (int i = 0; i < 8; ++i) {
      const int e = i * 256 + tid;
      const int r = e >> 5, c = e & 31;
      const int mrow = m0 + r;
      const int col = k0 + c;
      float a;
      if (AMODE == 0) {
        a = A[mrow * K + col];
      } else {
        const int bn = mrow >> 8, s = mrow & 255;
        const int b = bn >> 5, n = bn & 31;
        a = seq[((((b << 8) + s) << 5) + n) * 256 + col];
        if (AMODE == 2) a += ts[(((b << 8) + s) << 8) + col];
      }
      As[c][r] = a;
    }
    // stage W tile: 32 rows x 64 cols, coalesced
#pragma unroll
    for (int i = 0; i < 8; ++i) {
      const int e = i * 256 + tid;
      const int r = e >> 6, c = e & 63;
      Ws[r][c] = W[(k0 + r) * NOUT + n0 + c];
    }
    __syncthreads();
#pragma unroll
    for (int kk = 0; kk < 32; ++kk) {
      const float4 a4 = *(const float4*)&As[kk][tm * 4];
      const float4 w4 = *(const float4*)&Ws[kk][tn * 4];
      const float av[4] = {a4.x, a4.y, a4.z, a4.w};
      const float wv[4] = {w4.x, w4.y, w4.z, w4.w};
#pragma unroll
      for (int i = 0; i < 4; ++i)
#pragma unroll
        for (int j = 0; j < 4; ++j)
          acc[i][j] += av[i] * wv[j];
    }
    __syncthreads();
  }

  // epilogue
#pragma unroll
  for (int i = 0; i < 4; ++i) {
    const int row = m0 + tm * 4 + i;
    float vals[4];
#pragma unroll
    for (int j = 0; j < 4; ++j) {
      const int col = n0 + tn * 4 + j;
      float cacc = (acc[i][j] + bias[col]) * post_scale;
      if (RESMODE == 1) {
        const int bn = row >> 8, s = row & 255;
        const int b = bn >> 5, n = bn & 31;
        cacc += seq[((((b << 8) + s) << 5) + n) * 256 + col];
      } else if (RESMODE == 2) {
        cacc += res[row * NOUT + col];
      }
      if (GELU) cacc = 0.5f * cacc * (1.0f + erff(cacc * 0.70710678118654752f));
      vals[j] = cacc;
    }
    float4 outv = make_float4(vals[0], vals[1], vals[2], vals[3]);
    *(float4*)&C[row * NOUT + n0 + tn * 4] = outv;
  }
}

// ---------------------------------------------------------------------------
// Attention: one block per (bn, head). Thread t = query row.
// Augmented dot: q' = [q, 0.25*tq] (0.25 folded at tq projection),
// k' = [k, tk]; score = dot64 * 1/sqrt(32). Masked entries exactly -10000.
// Online softmax per thread; renorm by sum(p*valid) (softmax Z cancels).
// ---------------------------------------------------------------------------
__global__ __launch_bounds__(256)
void attn_kernel(const float* __restrict__ q, const float* __restrict__ k,
                 const float* __restrict__ v, const float* __restrict__ tq,
                 const float* __restrict__ tk, const int* __restrict__ valid,
                 float* __restrict__ ao) {
  __shared__ float Kt[64][64];    // [key][d64]  (k | tk)
  __shared__ float Vt[64][32];
  __shared__ float vmask[256];
  const int bh = blockIdx.x;
  const int bn = bh >> 3, h = bh & 7;
  const int b = bn >> 5, n = bn & 31;
  const int t = threadIdx.x;   // query index

  vmask[t] = (valid[((b << 8) + t) * 32 + n] != 0) ? 1.0f : 0.0f;

  float qr[64];
#pragma unroll
  for (int d0 = 0; d0 < 32; d0 += 4) {
    const float4 a = *(const float4*)&q[(((bn << 8) + t) << 8) + (h << 5) + d0];
    const float4 c = *(const float4*)&tq[(((b << 8) + t) << 8) + (h << 5) + d0];
    qr[d0] = a.x; qr[d0 + 1] = a.y; qr[d0 + 2] = a.z; qr[d0 + 3] = a.w;
    qr[32 + d0] = c.x; qr[32 + d0 + 1] = c.y; qr[32 + d0 + 2] = c.z; qr[32 + d0 + 3] = c.w;
  }

  const float scale = 0.17677669529663688f;  // 1/sqrt(32)
  float m = -10000.0f, l = 0.0f;
  float o[32];
#pragma unroll
  for (int d = 0; d < 32; ++d) o[d] = 0.f;

  for (int t0 = 0; t0 < 256; t0 += 64) {
    __syncthreads();
#pragma unroll
    for (int i = 0; i < 8; ++i) {
      const int e = i * 256 + t;
      const int s = e >> 5, d = e & 31;
      const int sg = t0 + s;
      Kt[s][d]      = k[(((bn << 8) + sg) << 8) + (h << 5) + d];
      Kt[s][32 + d] = tk[(((b << 8) + sg) << 8) + (h << 5) + d];
      Vt[s][d]      = v[(((bn << 8) + sg) << 8) + (h << 5) + d];
    }
    __syncthreads();
    int kmax = t - t0; if (kmax > 63) kmax = 63;
    for (int kk = 0; kk <= kmax; ++kk) {
      float acc = 0.f;
#pragma unroll
      for (int d0 = 0; d0 < 64; d0 += 4) {
        const float4 k4 = *(const float4*)&Kt[kk][d0];
        acc += qr[d0] * k4.x + qr[d0 + 1] * k4.y
             + qr[d0 + 2] * k4.z + qr[d0 + 3] * k4.w;
      }
      const float vd = vmask[t0 + kk];
      const float sc = (vd > 0.f) ? acc * scale : -10000.0f;
      if (sc > m) {  // rare (~log S times)
        const float r = __expf(m - sc);
        l *= r;
#pragma unroll
        for (int d = 0; d < 32; ++d) o[d] *= r;
        m = sc;
      }
      const float w = __expf(sc - m) * vd;
      l += w;
#pragma unroll
      for (int d0 = 0; d0 < 32; d0 += 4) {
        const float4 v4 = *(const float4*)&Vt[kk][d0];
        o[d0] += w * v4.x; o[d0 + 1] += w * v4.y;
        o[d0 + 2] += w * v4.z; o[d0 + 3] += w * v4.w;
      }
    }
  }

  // Degenerate row: no valid causal key -> uniform over ALL valid keys
  // (matches reference: all scores == -10000 -> softmax uniform -> *valid -> renorm)
  if (l == 0.0f) {
    for (int kk = 0; kk < 256; ++kk) {
      const float vd = vmask[kk];
      if (vd > 0.f) {
        l += 1.0f;
#pragma unroll
        for (int d = 0; d < 32; ++d)
          o[d] += v[(((bn << 8) + kk) << 8) + (h << 5) + d];
      }
    }
  }

  const float inv = 1.0f / fmaxf(l, 1e-30f);
#pragma unroll
  for (int d0 = 0; d0 < 32; d0 += 4) {
    float4 outv = make_float4(o[d0] * inv, o[d0 + 1] * inv,
                              o[d0 + 2] * inv, o[d0 + 3] * inv);
    *(float4*)&ao[(((bn << 8) + t) << 8) + (h << 5) + d0] = outv;
  }
}

// ---------------------------------------------------------------------------
// LayerNorm over H=256. One wave per row (4 rows/block).
// FINAL: multiply by valid mask and scatter to output layout [B,S,N,H].
// ---------------------------------------------------------------------------
template<bool FINAL>
__global__ __launch_bounds__(256)
void ln_kernel(const float* X, const float* __restrict__ g,
               const float* __restrict__ bb, float* out,
               const int* __restrict__ valid) {
  const int row = blockIdx.x * 4 + (threadIdx.x >> 6);
  const int lane = threadIdx.x & 63;
  const float4 x = *(const float4*)&X[row * 256 + lane * 4];
  float s1 = x.x + x.y + x.z + x.w;
#pragma unroll
  for (int off = 1; off < 64; off <<= 1) s1 += __shfl_xor(s1, off);
  const float mean = s1 * (1.0f / 256.0f);
  const float dx = x.x - mean, dy = x.y - mean, dz = x.z - mean, dw = x.w - mean;
  float s2 = dx * dx + dy * dy + dz * dz + dw * dw;
#pragma unroll
  for (int off = 1; off < 64; off <<= 1) s2 += __shfl_xor(s2, off);
  const float rstd = rsqrtf(s2 * (1.0f / 256.0f) + 1e-5f);
  const int c0 = lane * 4;
  float4 y;
  y.x = dx * rstd * g[c0] + bb[c0];
  y.y = dy * rstd * g[c0 + 1] + bb[c0 + 1];
  y.z = dz * rstd * g[c0 + 2] + bb[c0 + 2];
  y.w = dw * rstd * g[c0 + 3] + bb[c0 + 3];
  if (FINAL) {
    const int bn = row >> 8, s = row & 255;
    const int b = bn >> 5, n = bn & 31;
    const float vm = (valid[((b << 8) + s) * 32 + n] != 0) ? 1.0f : 0.0f;
    y.x *= vm; y.y *= vm; y.z *= vm; y.w *= vm;
    *(float4*)&out[(((((b << 8) + s) << 5) + n) << 8) + c0] = y;
  } else {
    *(float4*)&out[row * 256 + c0] = y;
  }
}

// ---------------------------------------------------------------------------
extern "C" void kernel_launch(void* const* d_in, const int* in_sizes, int n_in,
                              void* d_out, int out_size, void* d_ws, size_t ws_size,
                              hipStream_t stream) {
  const float* seq    = (const float*)d_in[0];
  const float* regs   = (const float*)d_in[1];
  const float* trs    = (const float*)d_in[2];
  const float* q_w    = (const float*)d_in[3];
  const float* q_b    = (const float*)d_in[4];
  const float* k_w    = (const float*)d_in[5];
  const float* k_b    = (const float*)d_in[6];
  const float* v_w    = (const float*)d_in[7];
  const float* v_b    = (const float*)d_in[8];
  const float* o_w    = (const float*)d_in[9];
  const float* o_b    = (const float*)d_in[10];
  const float* semb   = (const float*)d_in[11];
  const float* reg_w  = (const float*)d_in[12];
  const float* reg_b  = (const float*)d_in[13];
  const float* tr_w   = (const float*)d_in[14];
  const float* tr_b   = (const float*)d_in[15];
  const float* tq_w   = (const float*)d_in[16];
  const float* tq_b   = (const float*)d_in[17];
  const float* tk_w   = (const float*)d_in[18];
  const float* tk_b   = (const float*)d_in[19];
  const float* ff_w1  = (const float*)d_in[20];
  const float* ff_b1  = (const float*)d_in[21];
  const float* ff_w2  = (const float*)d_in[22];
  const float* ff_b2  = (const float*)d_in[23];
  const float* ln1_g  = (const float*)d_in[24];
  const float* ln1_b  = (const float*)d_in[25];
  const float* ln2_g  = (const float*)d_in[26];
  const float* ln2_b  = (const float*)d_in[27];
  const int*   valid  = (const int*)d_in[28];
  const int*   codes  = (const int*)d_in[29];

  float* ws = (float*)d_ws;
  float* ts  = ws;                  // 262144
  float* tq  = ws + 262144;         // 262144
  float* tk  = ws + 524288;         // 262144
  float* qb  = ws + 786432;         // 8388608
  float* kb  = ws + 9175040;        // 8388608
  float* vb  = ws + 17563648;       // 8388608
  float* ao  = ws + 25952256;       // 8388608  (total 34340864 floats = 137.4 MB)
  float* x1  = qb;                  // reuse: q dead after attention
  float* h1  = kb;                  // reuse: k+v contiguous = 16777216 floats
  float* x2  = ao;                  // reuse: ao dead after o-proj
  float* outp = (float*)d_out;

  // 1. time state (B*S rows, shared across N)
  ts_kernel<<<BS_, 256, 0, stream>>>(regs, trs, codes, semb, reg_w, reg_b,
                                     tr_w, tr_b, ts);
  // 2. temporal projections (0.25 score coefficient folded into tq)
  mm_kernel<0, 0, false, 256, 256><<<dim3(16, 4), 256, 0, stream>>>(
      ts, tq_w, tq_b, nullptr, nullptr, nullptr, tq, 0.25f);
  mm_kernel<0, 0, false, 256, 256><<<dim3(16, 4), 256, 0, stream>>>(
      ts, tk_w, tk_b, nullptr, nullptr, nullptr, tk, 1.0f);
  // 3. q/k/v projections (q,k input = flat + ts; v input = flat)
  mm_kernel<2, 0, false, 256, 256><<<dim3(512, 4), 256, 0, stream>>>(
      nullptr, q_w, q_b, seq, ts, nullptr, qb, 1.0f);
  mm_kernel<2, 0, false, 256, 256><<<dim3(512, 4), 256, 0, stream>>>(
      nullptr, k_w, k_b, seq, ts, nullptr, kb, 1.0f);
  mm_kernel<1, 0, false, 256, 256><<<dim3(512, 4), 256, 0, stream>>>(
      nullptr, v_w, v_b, seq, nullptr, nullptr, vb, 1.0f);
  // 4. attention
  attn_kernel<<<BN_ * NH_, 256, 0, stream>>>(qb, kb, vb, tq, tk, valid, ao);
  // 5. o-proj + residual(flat) -> x1 ; LN1 in-place
  mm_kernel<0, 1, false, 256, 256><<<dim3(512, 4), 256, 0, stream>>>(
      ao, o_w, o_b, seq, nullptr, nullptr, x1, 1.0f);
  ln_kernel<false><<<M_ / 4, 256, 0, stream>>>(x1, ln1_g, ln1_b, x1, nullptr);
  // 6. FF
  mm_kernel<0, 0, true, 256, 512><<<dim3(512, 8), 256, 0, stream>>>(
      x1, ff_w1, ff_b1, nullptr, nullptr, nullptr, h1, 1.0f);
  mm_kernel<0, 2, false, 512, 256><<<dim3(512, 4), 256, 0, stream>>>(
      h1, ff_w2, ff_b2, nullptr, nullptr, x1, x2, 1.0f);
  // 7. LN2 * valid -> output layout [B,S,N,H]
  ln_kernel<true><<<M_ / 4, 256, 0, stream>>>(x2, ln2_g, ln2_b, outp, valid);
}

// Round 2
// 460.949 us; speedup vs baseline: 1.9201x; 1.9201x over previous
//
#include <hip/hip_runtime.h>
#include <math.h>

// Shapes (fixed)
#define B_ 4
#define S_ 256
#define N_ 32
#define H_ 256
#define NH_ 8
#define HD_ 32
#define FF_ 512
#define BN_ 128
#define M_ 32768   // BN_*S_
#define BS_ 1024   // B_*S_

typedef __attribute__((ext_vector_type(8))) short short8;
typedef __attribute__((ext_vector_type(4))) short short4v;
typedef __attribute__((ext_vector_type(4))) float f32x4;

__device__ __forceinline__ unsigned short f2bf(float f) {
  unsigned u = __builtin_bit_cast(unsigned, f);
  u = (u + 0x7FFFu + ((u >> 16) & 1u)) >> 16;
  return (unsigned short)u;
}
__device__ __forceinline__ float bf2f(unsigned short h) {
  unsigned u = ((unsigned)h) << 16;
  return __builtin_bit_cast(float, u);
}

// ---------------------------------------------------------------------------
// time_state[bs, h] (fp32)
// ---------------------------------------------------------------------------
__global__ __launch_bounds__(256)
void ts_kernel(const float* __restrict__ reg, const float* __restrict__ tr,
               const int* __restrict__ codes,
               const float* __restrict__ sess_emb,
               const float* __restrict__ reg_w, const float* __restrict__ reg_b,
               const float* __restrict__ tr_w, const float* __restrict__ tr_b,
               float* __restrict__ ts) {
  const int bs = blockIdx.x;
  const int h = threadIdx.x;
  int c = codes[bs];
  c = c < 0 ? 0 : (c > 7 ? 7 : c);
  const float r = reg[bs], t = tr[bs];
  ts[bs * H_ + h] = sess_emb[c * H_ + h] + r * reg_w[h] + reg_b[h]
                    + t * tr_w[h] + tr_b[h];
}

// ---------------------------------------------------------------------------
// Weight convert + transpose: W[K][N] fp32 -> Wt[N][K] bf16
// ---------------------------------------------------------------------------
__global__ __launch_bounds__(256)
void cvtw_kernel(const float* __restrict__ W, unsigned short* __restrict__ Wt,
                 int nshift, int K) {
  const int idx = blockIdx.x * 256 + threadIdx.x;
  const int k = idx >> nshift, n = idx & ((1 << nshift) - 1);
  Wt[n * K + k] = f2bf(W[idx]);
}

// ---------------------------------------------------------------------------
// bf16 MFMA GEMM: C[M,NOUT] = epilogue(A @ W + bias)
// AMODE: 0 = fp32 A[M,K]; 1 = gather seq; 2 = gather seq+ts; 3 = bf16 A[M,K]
// RESMODE: 0 none; 1 + seq (fp32 gather); 2 + resb (bf16 [M,NOUT])
// OUTBF: write bf16 (else fp32). 128x128 tile, BK=64, 256 thr (4 waves 2x2).
// ---------------------------------------------------------------------------
template<int AMODE, int RESMODE, bool GELU_, int K, int NOUT, bool OUTBF>
__global__ __launch_bounds__(256)
void mmb_kernel(const void* __restrict__ Av, const unsigned short* __restrict__ Wt,
                const float* __restrict__ bias,
                const float* __restrict__ seq, const float* __restrict__ tsb,
                const unsigned short* __restrict__ resb,
                void* __restrict__ Cv, float post_scale) {
  __shared__ unsigned short As[128][72];
  __shared__ unsigned short Bs[128][72];
  const int tid = threadIdx.x;
  const int m0 = blockIdx.x * 128, n0 = blockIdx.y * 128;
  const int l = tid & 63, w = tid >> 6;
  const int wr = w >> 1, wc = w & 1;
  const int lr = l & 15, lg = l >> 4;
  f32x4 acc[4][4] = {};

  for (int k0 = 0; k0 < K; k0 += 64) {
    if (AMODE == 3) {
      const unsigned short* Ab = (const unsigned short*)Av;
#pragma unroll
      for (int i = 0; i < 4; ++i) {
        const int seg = i * 256 + tid;
        const int r = seg >> 3, c8 = (seg & 7) * 8;
        const short8 v = *(const short8*)&Ab[(m0 + r) * K + k0 + c8];
        *(short8*)&As[r][c8] = v;
      }
    } else {
#pragma unroll
      for (int i = 0; i < 8; ++i) {
        const int seg = i * 256 + tid;
        const int r = seg >> 4, c4 = (seg & 15) * 4;
        const int row = m0 + r;
        float4 a4;
        if (AMODE == 0) {
          a4 = *(const float4*)&((const float*)Av)[row * K + k0 + c4];
        } else {
          const int bn = row >> 8, s = row & 255;
          const int b = bn >> 5, n = bn & 31;
          a4 = *(const float4*)&seq[((((b << 8) + s) << 5) + n) * 256 + k0 + c4];
          if (AMODE == 2) {
            const float4 t4 = *(const float4*)&tsb[(((b << 8) + s) << 8) + k0 + c4];
            a4.x += t4.x; a4.y += t4.y; a4.z += t4.z; a4.w += t4.w;
          }
        }
        short4v sv;
        sv[0] = (short)f2bf(a4.x); sv[1] = (short)f2bf(a4.y);
        sv[2] = (short)f2bf(a4.z); sv[3] = (short)f2bf(a4.w);
        *(short4v*)&As[r][c4] = sv;
      }
    }
#pragma unroll
    for (int i = 0; i < 4; ++i) {
      const int seg = i * 256 + tid;
      const int n = seg >> 3, c8 = (seg & 7) * 8;
      const short8 v = *(const short8*)&Wt[(n0 + n) * K + k0 + c8];
      *(short8*)&Bs[n][c8] = v;
    }
    __syncthreads();
#pragma unroll
    for (int ks = 0; ks < 2; ++ks) {
      short8 af[4], bfr[4];
#pragma unroll
      for (int qt = 0; qt < 4; ++qt)
        af[qt] = *(const short8*)&As[wr * 64 + qt * 16 + lr][ks * 32 + lg * 8];
#pragma unroll
      for (int nt = 0; nt < 4; ++nt)
        bfr[nt] = *(const short8*)&Bs[wc * 64 + nt * 16 + lr][ks * 32 + lg * 8];
#pragma unroll
      for (int qt = 0; qt < 4; ++qt)
#pragma unroll
        for (int nt = 0; nt < 4; ++nt)
          acc[qt][nt] = __builtin_amdgcn_mfma_f32_16x16x32_bf16(
              af[qt], bfr[nt], acc[qt][nt], 0, 0, 0);
    }
    __syncthreads();
  }

  // epilogue: D element i -> row = base + lg*4 + i, col = base + lr
#pragma unroll
  for (int qt = 0; qt < 4; ++qt) {
#pragma unroll
    for (int nt = 0; nt < 4; ++nt) {
      const int col = n0 + wc * 64 + nt * 16 + lr;
      const float bsv = bias[col];
#pragma unroll
      for (int i = 0; i < 4; ++i) {
        const int row = m0 + wr * 64 + qt * 16 + (lg << 2) + i;
        float v = (acc[qt][nt][i] + bsv) * post_scale;
        if (RESMODE == 1) {
          const int bn = row >> 8, s = row & 255;
          const int b = bn >> 5, n = bn & 31;
          v += seq[((((b << 8) + s) << 5) + n) * 256 + col];
        } else if (RESMODE == 2) {
          v += bf2f(resb[row * NOUT + col]);
        }
        if (GELU_) v = 0.5f * v * (1.0f + erff(v * 0.70710678118654752f));
        if (OUTBF) ((unsigned short*)Cv)[row * NOUT + col] = f2bf(v);
        else       ((float*)Cv)[row * NOUT + col] = v;
      }
    }
  }
}

// ---------------------------------------------------------------------------
// MFMA flash attention. Block = (bn, h), 4 waves. Wave w owns query rows
// {qt*64 + w*16 + 0..15 : qt=0..3} (interleaved for causal balance).
// Aug dim 64: d<32 = q/k, d>=32 = 0.25*tq / tk. Exact reference masking.
// ---------------------------------------------------------------------------
__global__ __launch_bounds__(256)
void attn_mfma(const unsigned short* __restrict__ qb,
               const unsigned short* __restrict__ kb,
               const unsigned short* __restrict__ vb,
               const unsigned short* __restrict__ tqb,
               const unsigned short* __restrict__ tkb,
               const int* __restrict__ valid, unsigned short* __restrict__ ao) {
  __shared__ unsigned short Ks[64][72];   // [key][d64]
  __shared__ unsigned short Vs[32][72];   // [dv][key] (transposed)
  __shared__ unsigned short Ps[4][16][72];// per-wave P bounce [row16][key64]
  __shared__ float vm[256];
  const int bh = blockIdx.x;
  const int bn = bh >> 3, h = bh & 7;
  const int b = bn >> 5, n = bn & 31;
  const int tid = threadIdx.x, l = tid & 63, w = tid >> 6;
  const int lr = l & 15, lg = l >> 4;
  const float scale = 0.17677669529663688f;  // 1/sqrt(32)

  vm[tid] = (valid[((b << 8) + tid) * 32 + n] != 0) ? 1.0f : 0.0f;

  // Q fragments (A-layout: row = lr, k = lg*8..+8)
  short8 qf[4][2];
#pragma unroll
  for (int qt = 0; qt < 4; ++qt) {
    const int qrow = (bn << 8) + qt * 64 + w * 16 + lr;
    const int trow = (b << 8) + qt * 64 + w * 16 + lr;
    qf[qt][0] = *(const short8*)&qb[qrow * 256 + h * 32 + lg * 8];
    qf[qt][1] = *(const short8*)&tqb[trow * 256 + h * 32 + lg * 8];
  }

  f32x4 oacc[4][2] = {};
  float mrow[4][4], lsum[4][4];
#pragma unroll
  for (int qt = 0; qt < 4; ++qt)
#pragma unroll
    for (int i = 0; i < 4; ++i) { mrow[qt][i] = -10000.0f; lsum[qt][i] = 0.0f; }

  for (int t0 = 0; t0 < 256; t0 += 64) {
    __syncthreads();  // prior tile's LDS reads done (also covers vm)
    // stage Ks: 64 keys x 64 aug-d
#pragma unroll
    for (int i = 0; i < 2; ++i) {
      const int seg = i * 256 + tid;
      const int key = seg >> 3, c8 = (seg & 7) * 8;
      short8 v;
      if (c8 < 32) v = *(const short8*)&kb[((bn << 8) + t0 + key) * 256 + h * 32 + c8];
      else         v = *(const short8*)&tkb[((b << 8) + t0 + key) * 256 + h * 32 + (c8 - 32)];
      *(short8*)&Ks[key][c8] = v;
    }
    // stage Vs transposed
    {
      const int key = tid >> 2, ds = (tid & 3) * 8;
      const short8 v = *(const short8*)&vb[((bn << 8) + t0 + key) * 256 + h * 32 + ds];
#pragma unroll
      for (int j = 0; j < 8; ++j) Vs[ds + j][key] = (unsigned short)v[j];
    }
    __syncthreads();

    // V fragments (B-layout: col=dv=vt*16+lr, k=key)
    short8 vf[2][2];
#pragma unroll
    for (int ks2 = 0; ks2 < 2; ++ks2)
#pragma unroll
      for (int vt = 0; vt < 2; ++vt)
        vf[ks2][vt] = *(const short8*)&Vs[vt * 16 + lr][ks2 * 32 + lg * 8];

    // QK^T
    f32x4 sacc[4][4] = {};
#pragma unroll
    for (int kt = 0; kt < 4; ++kt) {
      const short8 kf0 = *(const short8*)&Ks[kt * 16 + lr][lg * 8];
      const short8 kf1 = *(const short8*)&Ks[kt * 16 + lr][32 + lg * 8];
#pragma unroll
      for (int qt = 0; qt < 4; ++qt) {
        if (t0 + kt * 16 <= qt * 64 + w * 16 + 15) {
          f32x4 z = {};
          z = __builtin_amdgcn_mfma_f32_16x16x32_bf16(qf[qt][0], kf0, z, 0, 0, 0);
          sacc[qt][kt] = __builtin_amdgcn_mfma_f32_16x16x32_bf16(qf[qt][1], kf1, z, 0, 0, 0);
        }
      }
    }

    // softmax + PV per query chunk
#pragma unroll
    for (int qt = 0; qt < 4; ++qt) {
      const int qb15 = qt * 64 + w * 16 + 15;
      if (t0 <= qb15) {
        float sm[4][4];
#pragma unroll
        for (int kt = 0; kt < 4; ++kt)
#pragma unroll
          for (int i = 0; i < 4; ++i) {
            const int key = t0 + kt * 16 + lr;
            const int r = qt * 64 + w * 16 + (lg << 2) + i;
            const bool mk = (key <= r) && (vm[key] > 0.0f);
            sm[kt][i] = mk ? sacc[qt][kt][i] * scale : -10000.0f;
          }
        float f4[4];
#pragma unroll
        for (int i = 0; i < 4; ++i) {
          float v = fmaxf(fmaxf(sm[0][i], sm[1][i]), fmaxf(sm[2][i], sm[3][i]));
          v = fmaxf(v, __shfl_xor(v, 1)); v = fmaxf(v, __shfl_xor(v, 2));
          v = fmaxf(v, __shfl_xor(v, 4)); v = fmaxf(v, __shfl_xor(v, 8));
          const float mo = mrow[qt][i];
          const float mn = fmaxf(mo, v);
          const float f = __expf(mo - mn);
          mrow[qt][i] = mn; f4[i] = f;
          float rs = 0.0f;
#pragma unroll
          for (int kt = 0; kt < 4; ++kt) {
            float p = __expf(sm[kt][i] - mn);
            p = (sm[kt][i] == -10000.0f) ? 0.0f : p;
            rs += p;
            Ps[w][(lg << 2) + i][kt * 16 + lr] = f2bf(p);
          }
          rs += __shfl_xor(rs, 1); rs += __shfl_xor(rs, 2);
          rs += __shfl_xor(rs, 4); rs += __shfl_xor(rs, 8);
          lsum[qt][i] = lsum[qt][i] * f + rs;
        }
#pragma unroll
        for (int vt = 0; vt < 2; ++vt)
#pragma unroll
          for (int i = 0; i < 4; ++i) oacc[qt][vt][i] *= f4[i];
        // PV (Ps write->read same wave: compiler inserts lgkmcnt)
#pragma unroll
        for (int ks2 = 0; ks2 < 2; ++ks2) {
          if (t0 + ks2 * 32 <= qb15) {
            const short8 pa = *(const short8*)&Ps[w][lr][ks2 * 32 + lg * 8];
#pragma unroll
            for (int vt = 0; vt < 2; ++vt)
              oacc[qt][vt] = __builtin_amdgcn_mfma_f32_16x16x32_bf16(
                  pa, vf[ks2][vt], oacc[qt][vt], 0, 0, 0);
          }
        }
      }
    }
  }

  // degenerate rows: no valid causal key -> uniform over ALL valid keys
#pragma unroll
  for (int qt = 0; qt < 4; ++qt)
#pragma unroll
    for (int i = 0; i < 4; ++i) {
      if (lsum[qt][i] == 0.0f) {
        float o0 = 0.f, o1 = 0.f, cnt = 0.f;
        for (int key = 0; key < 256; ++key) {
          if (vm[key] > 0.0f) {
            cnt += 1.0f;
            o0 += bf2f(vb[((bn << 8) + key) * 256 + h * 32 + lr]);
            o1 += bf2f(vb[((bn << 8) + key) * 256 + h * 32 + 16 + lr]);
          }
        }
        oacc[qt][0][i] = o0; oacc[qt][1][i] = o1; lsum[qt][i] = cnt;
      }
    }

  // store
#pragma unroll
  for (int qt = 0; qt < 4; ++qt)
#pragma unroll
    for (int i = 0; i < 4; ++i) {
      const int r = qt * 64 + w * 16 + (lg << 2) + i;
      const float inv = 1.0f / fmaxf(lsum[qt][i], 1e-6f);
#pragma unroll
      for (int vt = 0; vt < 2; ++vt)
        ao[((bn << 8) + r) * 256 + h * 32 + vt * 16 + lr] =
            f2bf(oacc[qt][vt][i] * inv);
    }
}

// ---------------------------------------------------------------------------
// LN1: fp32 in -> bf16 out (flat). LN2: fp32 in -> fp32 out, *valid, scatter.
// ---------------------------------------------------------------------------
__global__ __launch_bounds__(256)
void ln1_kernel(const float* __restrict__ X, const float* __restrict__ g,
                const float* __restrict__ bb, unsigned short* __restrict__ out) {
  const int row = blockIdx.x * 4 + (threadIdx.x >> 6);
  const int lane = threadIdx.x & 63;
  const float4 x = *(const float4*)&X[row * 256 + lane * 4];
  float s1 = x.x + x.y + x.z + x.w;
#pragma unroll
  for (int off = 1; off < 64; off <<= 1) s1 += __shfl_xor(s1, off);
  const float mean = s1 * (1.0f / 256.0f);
  const float dx = x.x - mean, dy = x.y - mean, dz = x.z - mean, dw = x.w - mean;
  float s2 = dx * dx + dy * dy + dz * dz + dw * dw;
#pragma unroll
  for (int off = 1; off < 64; off <<= 1) s2 += __shfl_xor(s2, off);
  const float rstd = rsqrtf(s2 * (1.0f / 256.0f) + 1e-5f);
  const int c0 = lane * 4;
  short4v y;
  y[0] = (short)f2bf(dx * rstd * g[c0] + bb[c0]);
  y[1] = (short)f2bf(dy * rstd * g[c0 + 1] + bb[c0 + 1]);
  y[2] = (short)f2bf(dz * rstd * g[c0 + 2] + bb[c0 + 2]);
  y[3] = (short)f2bf(dw * rstd * g[c0 + 3] + bb[c0 + 3]);
  *(short4v*)&out[row * 256 + c0] = y;
}

__global__ __launch_bounds__(256)
void ln2_kernel(const float* __restrict__ X, const float* __restrict__ g,
                const float* __restrict__ bb, float* __restrict__ out,
                const int* __restrict__ valid) {
  const int row = blockIdx.x * 4 + (threadIdx.x >> 6);
  const int lane = threadIdx.x & 63;
  const float4 x = *(const float4*)&X[row * 256 + lane * 4];
  float s1 = x.x + x.y + x.z + x.w;
#pragma unroll
  for (int off = 1; off < 64; off <<= 1) s1 += __shfl_xor(s1, off);
  const float mean = s1 * (1.0f / 256.0f);
  const float dx = x.x - mean, dy = x.y - mean, dz = x.z - mean, dw = x.w - mean;
  float s2 = dx * dx + dy * dy + dz * dz + dw * dw;
#pragma unroll
  for (int off = 1; off < 64; off <<= 1) s2 += __shfl_xor(s2, off);
  const float rstd = rsqrtf(s2 * (1.0f / 256.0f) + 1e-5f);
  const int c0 = lane * 4;
  const int bn = row >> 8, s = row & 255;
  const int b = bn >> 5, n = bn & 31;
  const float vmv = (valid[((b << 8) + s) * 32 + n] != 0) ? 1.0f : 0.0f;
  float4 y;
  y.x = (dx * rstd * g[c0] + bb[c0]) * vmv;
  y.y = (dy * rstd * g[c0 + 1] + bb[c0 + 1]) * vmv;
  y.z = (dz * rstd * g[c0 + 2] + bb[c0 + 2]) * vmv;
  y.w = (dw * rstd * g[c0 + 3] + bb[c0 + 3]) * vmv;
  *(float4*)&out[(((((b << 8) + s) << 5) + n) << 8) + c0] = y;
}

// ---------------------------------------------------------------------------
extern "C" void kernel_launch(void* const* d_in, const int* in_sizes, int n_in,
                              void* d_out, int out_size, void* d_ws, size_t ws_size,
                              hipStream_t stream) {
  const float* seq    = (const float*)d_in[0];
  const float* regs   = (const float*)d_in[1];
  const float* trs    = (const float*)d_in[2];
  const float* q_w    = (const float*)d_in[3];
  const float* q_b    = (const float*)d_in[4];
  const float* k_w    = (const float*)d_in[5];
  const float* k_b    = (const float*)d_in[6];
  const float* v_w    = (const float*)d_in[7];
  const float* v_b    = (const float*)d_in[8];
  const float* o_w    = (const float*)d_in[9];
  const float* o_b    = (const float*)d_in[10];
  const float* semb   = (const float*)d_in[11];
  const float* reg_w  = (const float*)d_in[12];
  const float* reg_b  = (const float*)d_in[13];
  const float* tr_w   = (const float*)d_in[14];
  const float* tr_b   = (const float*)d_in[15];
  const float* tq_w   = (const float*)d_in[16];
  const float* tq_b   = (const float*)d_in[17];
  const float* tk_w   = (const float*)d_in[18];
  const float* tk_b   = (const float*)d_in[19];
  const float* ff_w1  = (const float*)d_in[20];
  const float* ff_b1  = (const float*)d_in[21];
  const float* ff_w2  = (const float*)d_in[22];
  const float* ff_b2  = (const float*)d_in[23];
  const float* ln1_g  = (const float*)d_in[24];
  const float* ln1_b  = (const float*)d_in[25];
  const float* ln2_g  = (const float*)d_in[26];
  const float* ln2_b  = (const float*)d_in[27];
  const int*   valid  = (const int*)d_in[28];
  const int*   codes  = (const int*)d_in[29];

  float* f32ws = (float*)d_ws;
  float* ts    = f32ws;                 // 262144 f
  float* x1pre = f32ws + 262144;        // 8388608 f (reused as x2)
  unsigned short* bws = (unsigned short*)(f32ws + 262144 + 8388608);
  unsigned short* qb   = bws;                 // 8388608 (reused as x1b)
  unsigned short* kb   = bws + 8388608;       // 8388608 (reused as h1 lo)
  unsigned short* vb   = bws + 16777216;      // 8388608 (reused as h1 hi)
  unsigned short* ao   = bws + 25165824;      // 8388608
  unsigned short* tqb  = bws + 33554432;      // 262144
  unsigned short* tkb  = bws + 33816576;      // 262144
  unsigned short* wq   = bws + 34078720;      // 65536
  unsigned short* wk   = bws + 34144256;
  unsigned short* wv   = bws + 34209792;
  unsigned short* wo   = bws + 34275328;
  unsigned short* wtq  = bws + 34340864;
  unsigned short* wtk  = bws + 34406400;
  unsigned short* wff1 = bws + 34471936;      // 131072
  unsigned short* wff2 = bws + 34603008;      // 131072
  unsigned short* x1b  = qb;
  unsigned short* h1   = kb;                  // kb+vb contiguous 16777216
  float* x2 = x1pre;
  float* outp = (float*)d_out;

  // 1. time state
  ts_kernel<<<BS_, 256, 0, stream>>>(regs, trs, codes, semb, reg_w, reg_b,
                                     tr_w, tr_b, ts);
  // 2. weight conversion (bf16, transposed [N][K])
  cvtw_kernel<<<256, 256, 0, stream>>>(q_w, wq, 8, 256);
  cvtw_kernel<<<256, 256, 0, stream>>>(k_w, wk, 8, 256);
  cvtw_kernel<<<256, 256, 0, stream>>>(v_w, wv, 8, 256);
  cvtw_kernel<<<256, 256, 0, stream>>>(o_w, wo, 8, 256);
  cvtw_kernel<<<256, 256, 0, stream>>>(tq_w, wtq, 8, 256);
  cvtw_kernel<<<256, 256, 0, stream>>>(tk_w, wtk, 8, 256);
  cvtw_kernel<<<512, 256, 0, stream>>>(ff_w1, wff1, 9, 256);
  cvtw_kernel<<<512, 256, 0, stream>>>(ff_w2, wff2, 8, 512);
  // 3. temporal projections (0.25 folded into tq)
  mmb_kernel<0, 0, false, 256, 256, true><<<dim3(8, 2), 256, 0, stream>>>(
      ts, wtq, tq_b, nullptr, nullptr, nullptr, tqb, 0.25f);
  mmb_kernel<0, 0, false, 256, 256, true><<<dim3(8, 2), 256, 0, stream>>>(
      ts, wtk, tk_b, nullptr, nullptr, nullptr, tkb, 1.0f);
  // 4. q/k/v projections
  mmb_kernel<2, 0, false, 256, 256, true><<<dim3(256, 2), 256, 0, stream>>>(
      nullptr, wq, q_b, seq, ts, nullptr, qb, 1.0f);
  mmb_kernel<2, 0, false, 256, 256, true><<<dim3(256, 2), 256, 0, stream>>>(
      nullptr, wk, k_b, seq, ts, nullptr, kb, 1.0f);
  mmb_kernel<1, 0, false, 256, 256, true><<<dim3(256, 2), 256, 0, stream>>>(
      nullptr, wv, v_b, seq, nullptr, nullptr, vb, 1.0f);
  // 5. attention
  attn_mfma<<<BN_ * NH_, 256, 0, stream>>>(qb, kb, vb, tqb, tkb, valid, ao);
  // 6. o-proj + seq residual -> x1pre (fp32); LN1 -> x1b (bf16)
  mmb_kernel<3, 1, false, 256, 256, false><<<dim3(256, 2), 256, 0, stream>>>(
      ao, wo, o_b, seq, nullptr, nullptr, x1pre, 1.0f);
  ln1_kernel<<<M_ / 4, 256, 0, stream>>>(x1pre, ln1_g, ln1_b, x1b);
  // 7. FF
  mmb_kernel<3, 0, true, 256, 512, true><<<dim3(256, 4), 256, 0, stream>>>(
      x1b, wff1, ff_b1, nullptr, nullptr, nullptr, h1, 1.0f);
  mmb_kernel<3, 2, false, 512, 256, false><<<dim3(256, 2), 256, 0, stream>>>(
      h1, wff2, ff_b2, nullptr, nullptr, x1b, x2, 1.0f);
  // 8. LN2 * valid -> output layout
  ln2_kernel<<<M_ / 4, 256, 0, stream>>>(x2, ln2_g, ln2_b, outp, valid);
}

// Round 5
// 274.008 us; speedup vs baseline: 3.2301x; 1.6822x over previous
//
#include <hip/hip_runtime.h>
#include <math.h>

// Shapes (fixed)
#define B_ 4
#define S_ 256
#define N_ 32
#define H_ 256
#define NH_ 8
#define HD_ 32
#define FF_ 512
#define BN_ 128
#define M_ 32768   // BN_*S_
#define BS_ 1024   // B_*S_

typedef __attribute__((ext_vector_type(8))) short short8;
typedef __attribute__((ext_vector_type(4))) short short4v;
typedef __attribute__((ext_vector_type(4))) float f32x4;
typedef __attribute__((ext_vector_type(16))) float f32x16;
typedef __attribute__((ext_vector_type(2))) unsigned long long u64x2;

__device__ __forceinline__ unsigned short f2bf(float f) {
  unsigned u = __builtin_bit_cast(unsigned, f);
  u = (u + 0x7FFFu + ((u >> 16) & 1u)) >> 16;
  return (unsigned short)u;
}
__device__ __forceinline__ float bf2f(unsigned short h) {
  unsigned u = ((unsigned)h) << 16;
  return __builtin_bit_cast(float, u);
}

// ---------------------------------------------------------------------------
// time_state[bs, h] (fp32)
// ---------------------------------------------------------------------------
__global__ __launch_bounds__(256)
void ts_kernel(const float* __restrict__ reg, const float* __restrict__ tr,
               const int* __restrict__ codes,
               const float* __restrict__ sess_emb,
               const float* __restrict__ reg_w, const float* __restrict__ reg_b,
               const float* __restrict__ tr_w, const float* __restrict__ tr_b,
               float* __restrict__ ts) {
  const int bs = blockIdx.x;
  const int h = threadIdx.x;
  int c = codes[bs];
  c = c < 0 ? 0 : (c > 7 ? 7 : c);
  const float r = reg[bs], t = tr[bs];
  ts[bs * H_ + h] = sess_emb[c * H_ + h] + r * reg_w[h] + reg_b[h]
                    + t * tr_w[h] + tr_b[h];
}

// ---------------------------------------------------------------------------
// Weight convert + transpose: W[K][N] fp32 -> Wt[N][K] bf16
// ---------------------------------------------------------------------------
__global__ __launch_bounds__(256)
void cvtw_kernel(const float* __restrict__ W, unsigned short* __restrict__ Wt,
                 int nshift, int K) {
  const int idx = blockIdx.x * 256 + threadIdx.x;
  const int k = idx >> nshift, n = idx & ((1 << nshift) - 1);
  Wt[n * K + k] = f2bf(W[idx]);
}

// ---------------------------------------------------------------------------
// bf16 MFMA GEMM: C[M,NOUT] = epilogue(A @ W + bias)
// AMODE: 0 = fp32 A[M,K]; 1 = gather seq; 2 = gather seq+ts; 3 = bf16 A[M,K]
// RESMODE: 0 none; 1 + seq (fp32 gather); 2 + resb (bf16 [M,NOUT])
// OUTBF: write bf16 (else fp32). 128x128 tile, BK=64, 256 thr (4 waves 2x2).
// ---------------------------------------------------------------------------
template<int AMODE, int RESMODE, bool GELU_, int K, int NOUT, bool OUTBF>
__global__ __launch_bounds__(256)
void mmb_kernel(const void* __restrict__ Av, const unsigned short* __restrict__ Wt,
                const float* __restrict__ bias,
                const float* __restrict__ seq, const float* __restrict__ tsb,
                const unsigned short* __restrict__ resb,
                void* __restrict__ Cv, float post_scale) {
  __shared__ unsigned short As[128][72];
  __shared__ unsigned short Bs[128][72];
  const int tid = threadIdx.x;
  const int m0 = blockIdx.x * 128, n0 = blockIdx.y * 128;
  const int l = tid & 63, w = tid >> 6;
  const int wr = w >> 1, wc = w & 1;
  const int lr = l & 15, lg = l >> 4;
  f32x4 acc[4][4] = {};

  for (int k0 = 0; k0 < K; k0 += 64) {
    if (AMODE == 3) {
      const unsigned short* Ab = (const unsigned short*)Av;
#pragma unroll
      for (int i = 0; i < 4; ++i) {
        const int seg = i * 256 + tid;
        const int r = seg >> 3, c8 = (seg & 7) * 8;
        const short8 v = *(const short8*)&Ab[(m0 + r) * K + k0 + c8];
        *(short8*)&As[r][c8] = v;
      }
    } else {
#pragma unroll
      for (int i = 0; i < 8; ++i) {
        const int seg = i * 256 + tid;
        const int r = seg >> 4, c4 = (seg & 15) * 4;
        const int row = m0 + r;
        float4 a4;
        if (AMODE == 0) {
          a4 = *(const float4*)&((const float*)Av)[row * K + k0 + c4];
        } else {
          const int bn = row >> 8, s = row & 255;
          const int b = bn >> 5, n = bn & 31;
          a4 = *(const float4*)&seq[((((b << 8) + s) << 5) + n) * 256 + k0 + c4];
          if (AMODE == 2) {
            const float4 t4 = *(const float4*)&tsb[(((b << 8) + s) << 8) + k0 + c4];
            a4.x += t4.x; a4.y += t4.y; a4.z += t4.z; a4.w += t4.w;
          }
        }
        short4v sv;
        sv[0] = (short)f2bf(a4.x); sv[1] = (short)f2bf(a4.y);
        sv[2] = (short)f2bf(a4.z); sv[3] = (short)f2bf(a4.w);
        *(short4v*)&As[r][c4] = sv;
      }
    }
#pragma unroll
    for (int i = 0; i < 4; ++i) {
      const int seg = i * 256 + tid;
      const int n = seg >> 3, c8 = (seg & 7) * 8;
      const short8 v = *(const short8*)&Wt[(n0 + n) * K + k0 + c8];
      *(short8*)&Bs[n][c8] = v;
    }
    __syncthreads();
#pragma unroll
    for (int ks = 0; ks < 2; ++ks) {
      short8 af[4], bfr[4];
#pragma unroll
      for (int qt = 0; qt < 4; ++qt)
        af[qt] = *(const short8*)&As[wr * 64 + qt * 16 + lr][ks * 32 + lg * 8];
#pragma unroll
      for (int nt = 0; nt < 4; ++nt)
        bfr[nt] = *(const short8*)&Bs[wc * 64 + nt * 16 + lr][ks * 32 + lg * 8];
#pragma unroll
      for (int qt = 0; qt < 4; ++qt)
#pragma unroll
        for (int nt = 0; nt < 4; ++nt)
          acc[qt][nt] = __builtin_amdgcn_mfma_f32_16x16x32_bf16(
              af[qt], bfr[nt], acc[qt][nt], 0, 0, 0);
    }
    __syncthreads();
  }

  // epilogue: D element i -> row = base + lg*4 + i, col = base + lr
#pragma unroll
  for (int qt = 0; qt < 4; ++qt) {
#pragma unroll
    for (int nt = 0; nt < 4; ++nt) {
      const int col = n0 + wc * 64 + nt * 16 + lr;
      const float bsv = bias[col];
#pragma unroll
      for (int i = 0; i < 4; ++i) {
        const int row = m0 + wr * 64 + qt * 16 + (lg << 2) + i;
        float v = (acc[qt][nt][i] + bsv) * post_scale;
        if (RESMODE == 1) {
          const int bn = row >> 8, s = row & 255;
          const int b = bn >> 5, n = bn & 31;
          v += seq[((((b << 8) + s) << 5) + n) * 256 + col];
        } else if (RESMODE == 2) {
          v += bf2f(resb[row * NOUT + col]);
        }
        if (GELU_) v = 0.5f * v * (1.0f + erff(v * 0.70710678118654752f));
        if (OUTBF) ((unsigned short*)Cv)[row * NOUT + col] = f2bf(v);
        else       ((float*)Cv)[row * NOUT + col] = v;
      }
    }
  }
}

// ---------------------------------------------------------------------------
// Attention v3: swapped-operand 32x32 MFMA flash, 8 waves x 32 query rows.
// S^T = mfma(K', Q') -> lane owns one query column; softmax in-lane +
// __shfl_xor(.,32). P redistributed through a per-wave LDS bounce (no
// permlane / cvt_pk semantics dependencies). O^T = mfma(V^T, P).
// One block-wide barrier total.
// ---------------------------------------------------------------------------
__global__ __launch_bounds__(512, 4)
void attn2_kernel(const unsigned short* __restrict__ qb,
                  const unsigned short* __restrict__ kb,
                  const unsigned short* __restrict__ vb,
                  const unsigned short* __restrict__ tqb,
                  const unsigned short* __restrict__ tkb,
                  const int* __restrict__ valid,
                  unsigned short* __restrict__ ao) {
  __shared__ __align__(16) char KsB[256 * 128];   // K' [key][d64] bf16, swizzled
  __shared__ __align__(16) char VsB[32 * 512];    // V^T [dv][key] bf16, swizzled
  __shared__ __align__(16) char PwB[8 * 2048];    // per-wave P bounce [key32][q32]
                                                  // (reused as O bounce at end)

  const int bh = blockIdx.x;
  const int bn = bh >> 3, h = bh & 7;
  const int b = bn >> 5, n = bn & 31;
  const int tid = threadIdx.x, l = tid & 63, w = tid >> 6;
  const int lq = l & 31, hi = l >> 5;
  const int qa = w * 32 + lq;          // this lane's query row
  const float c2 = 0.25505402f;        // (1/sqrt(32)) * log2(e)

  // validity bitmask (wave-uniform)
  const unsigned long long bm0 = __ballot(valid[((b << 8) + 0   + l) * 32 + n] != 0);
  const unsigned long long bm1 = __ballot(valid[((b << 8) + 64  + l) * 32 + n] != 0);
  const unsigned long long bm2 = __ballot(valid[((b << 8) + 128 + l) * 32 + n] != 0);
  const unsigned long long bm3 = __ballot(valid[((b << 8) + 192 + l) * 32 + n] != 0);

  // Q' fragments (B-operand): col = own q, k = 8*hi + j per 16-wide K chunk
  short8 qf[4];
  {
    const unsigned short* qp = &qb[(((bn << 8) + qa) << 8) + (h << 5)];
    const unsigned short* tp = &tqb[(((b << 8) + qa) << 8) + (h << 5)];
    qf[0] = *(const short8*)&qp[hi * 8];
    qf[1] = *(const short8*)&qp[16 + hi * 8];
    qf[2] = *(const short8*)&tp[hi * 8];
    qf[3] = *(const short8*)&tp[16 + hi * 8];
  }

  // stage K' (k | tk), swizzled: byte = key*128 + ((c*16) ^ ((key&7)<<4))
#pragma unroll
  for (int i = 0; i < 4; ++i) {
    const int e = i * 512 + tid;
    const int key = e >> 3, c = e & 7;
    const unsigned short* src = (c < 4)
        ? &kb[(((bn << 8) + key) << 8) + (h << 5) + c * 8]
        : &tkb[(((b << 8) + key) << 8) + (h << 5) + (c - 4) * 8];
    *(short8*)(KsB + key * 128 + ((c * 16) ^ ((key & 7) << 4))) = *(const short8*)src;
  }
  // stage V^T, swizzled: byte = dv*512 + ((key*2) ^ ((dv&7)<<4))
#pragma unroll
  for (int i = 0; i < 2; ++i) {
    const int e = i * 512 + tid;
    const int key = e >> 2, c = e & 3;
    const short8 v = *(const short8*)&vb[(((bn << 8) + key) << 8) + (h << 5) + c * 8];
#pragma unroll
    for (int j = 0; j < 8; ++j) {
      const int dv = c * 8 + j;
      *(unsigned short*)(VsB + dv * 512 + ((key * 2) ^ ((dv & 7) << 4))) =
          (unsigned short)v[j];
    }
  }
  __syncthreads();

  f32x16 oacc = {};
  float mrun = -1e30f, lrun = 0.0f;
  const int ntile = (w >> 1) + 1;

  for (int t = 0; t < ntile; ++t) {
    const int t0 = t * 64;
#pragma unroll
    for (int kg = 0; kg < 2; ++kg) {
      const int kbase = t0 + kg * 32;
      if (kbase >= (w + 1) * 32) continue;
      // S^T = mfma(K'_tile, Q')
      f32x16 sacc = {};
#pragma unroll
      for (int df = 0; df < 4; ++df) {
        const int key = kbase + lq;
        const short8 akf = *(const short8*)(
            KsB + key * 128 + (((df * 32 + hi * 16)) ^ ((key & 7) << 4)));
        sacc = __builtin_amdgcn_mfma_f32_32x32x16_bf16(akf, qf[df], sacc, 0, 0, 0);
      }
      // mask + scale (log2 domain)
      const unsigned long long bmc = (kbase < 64) ? bm0 : (kbase < 128) ? bm1
                                   : (kbase < 192) ? bm2 : bm3;
      const unsigned wnd = (kbase & 32) ? (unsigned)(bmc >> 32) : (unsigned)bmc;
#pragma unroll
      for (int r = 0; r < 16; ++r) {
        const int crow = (r & 3) + 8 * (r >> 2) + 4 * hi;
        const int key = kbase + crow;
        const bool ok = (key <= qa) && (((wnd >> crow) & 1u) != 0u);
        sacc[r] = ok ? sacc[r] * c2 : -1e30f;
      }
      // group max: in-lane tree over 16, then cross-half combine via shfl
      float g0 = fmaxf(fmaxf(sacc[0], sacc[1]), fmaxf(sacc[2], sacc[3]));
      float g1 = fmaxf(fmaxf(sacc[4], sacc[5]), fmaxf(sacc[6], sacc[7]));
      float g2 = fmaxf(fmaxf(sacc[8], sacc[9]), fmaxf(sacc[10], sacc[11]));
      float g3 = fmaxf(fmaxf(sacc[12], sacc[13]), fmaxf(sacc[14], sacc[15]));
      float gmax = fmaxf(fmaxf(g0, g1), fmaxf(g2, g3));
      gmax = fmaxf(gmax, __shfl_xor(gmax, 32));
      const float mnew = fmaxf(mrun, gmax);
      const float f = __builtin_amdgcn_exp2f(mrun - mnew);
      mrun = mnew;
      lrun *= f;
#pragma unroll
      for (int r = 0; r < 16; ++r) oacc[r] *= f;
      // p = exp2(t - m), exact 0 for masked
#pragma unroll
      for (int r = 0; r < 16; ++r) {
        const float p = __builtin_amdgcn_exp2f(sacc[r] - mnew);
        sacc[r] = (sacc[r] < -1e29f) ? 0.0f : p;
      }
      float rs = ((sacc[0] + sacc[1]) + (sacc[2] + sacc[3]))
               + ((sacc[4] + sacc[5]) + (sacc[6] + sacc[7]))
               + ((sacc[8] + sacc[9]) + (sacc[10] + sacc[11]))
               + ((sacc[12] + sacc[13]) + (sacc[14] + sacc[15]));
      rs += __shfl_xor(rs, 32);
      lrun += rs;

      // P redistribution via per-wave LDS bounce: P[key32][q32] u16.
      // Write uses the HW-verified C/D mapping; per-r writes are
      // row-contiguous (64B / 32 lanes -> conflict-free).
#pragma unroll
      for (int r = 0; r < 16; ++r) {
        const int crow = (r & 3) + 8 * (r >> 2) + 4 * hi;
        *(unsigned short*)(PwB + w * 2048 + crow * 64 + lq * 2) = f2bf(sacc[r]);
      }
      asm volatile("" ::: "memory");  // keep program order (same-wave DS is in-order)
      // Read PV B-fragments: lane (lq,hi) needs P[8*hi + j][lq] (frag 0)
      // and P[16 + 8*hi + j][lq] (frag 1); row-contiguous reads.
      short8 pf0, pf1;
#pragma unroll
      for (int j = 0; j < 8; ++j) {
        pf0[j] = (short)*(const unsigned short*)(
            PwB + w * 2048 + (hi * 8 + j) * 64 + lq * 2);
        pf1[j] = (short)*(const unsigned short*)(
            PwB + w * 2048 + (16 + hi * 8 + j) * 64 + lq * 2);
      }
      // PV: O^T += mfma(V^T, P)
      {
        const short8 avf = *(const short8*)(
            VsB + lq * 512 + (((kbase + hi * 8) * 2) ^ ((lq & 7) << 4)));
        oacc = __builtin_amdgcn_mfma_f32_32x32x16_bf16(avf, pf0, oacc, 0, 0, 0);
      }
      {
        const short8 avf = *(const short8*)(
            VsB + lq * 512 + (((kbase + 16 + hi * 8) * 2) ^ ((lq & 7) << 4)));
        oacc = __builtin_amdgcn_mfma_f32_32x32x16_bf16(avf, pf1, oacc, 0, 0, 0);
      }
    }
  }

  // degenerate rows: no valid causal key -> uniform over ALL valid keys
  if (lrun == 0.0f) {
    float cnt = 0.0f;
    f32x16 os = {};
    for (int key = 0; key < 256; ++key) {
      const unsigned long long bmc = (key < 64) ? bm0 : (key < 128) ? bm1
                                   : (key < 192) ? bm2 : bm3;
      if ((bmc >> (key & 63)) & 1ull) {
        cnt += 1.0f;
#pragma unroll
        for (int r = 0; r < 16; ++r) {
          const int dv = (r & 3) + 8 * (r >> 2) + 4 * hi;
          os[r] += bf2f(*(const unsigned short*)(
              VsB + dv * 512 + ((key * 2) ^ ((dv & 7) << 4))));
        }
      }
    }
    oacc = os; lrun = cnt;
  }

  // write O (transpose via per-wave LDS bounce in PwB, swizzled rows)
  const float inv = 1.0f / fmaxf(lrun, 1e-6f);
#pragma unroll
  for (int r = 0; r < 16; ++r) {
    const int dv = (r & 3) + 8 * (r >> 2) + 4 * hi;
    *(unsigned short*)(PwB + w * 2048 + lq * 64 + ((dv * 2) ^ ((lq & 7) << 3))) =
        f2bf(oacc[r] * inv);
  }
  asm volatile("s_waitcnt lgkmcnt(0)" ::: "memory");
  {
    const int q2 = l >> 1, h2 = l & 1;
    unsigned long long d0, d1, d2, d3;
    d0 = *(const unsigned long long*)(PwB + w * 2048 + q2 * 64 + (((h2 * 4 + 0) ^ (q2 & 7)) << 3));
    d1 = *(const unsigned long long*)(PwB + w * 2048 + q2 * 64 + (((h2 * 4 + 1) ^ (q2 & 7)) << 3));
    d2 = *(const unsigned long long*)(PwB + w * 2048 + q2 * 64 + (((h2 * 4 + 2) ^ (q2 & 7)) << 3));
    d3 = *(const unsigned long long*)(PwB + w * 2048 + q2 * 64 + (((h2 * 4 + 3) ^ (q2 & 7)) << 3));
    u64x2 sv0, sv1;
    sv0[0] = d0; sv0[1] = d1; sv1[0] = d2; sv1[1] = d3;
    unsigned short* op = &ao[(((bn << 8) + w * 32 + q2) << 8) + (h << 5) + h2 * 16];
    *(u64x2*)op = sv0;
    *(u64x2*)(op + 8) = sv1;
  }
}

// ---------------------------------------------------------------------------
// LN1: fp32 in -> bf16 out (flat). LN2: fp32 in -> fp32 out, *valid, scatter.
// ---------------------------------------------------------------------------
__global__ __launch_bounds__(256)
void ln1_kernel(const float* __restrict__ X, const float* __restrict__ g,
                const float* __restrict__ bb, unsigned short* __restrict__ out) {
  const int row = blockIdx.x * 4 + (threadIdx.x >> 6);
  const int lane = threadIdx.x & 63;
  const float4 x = *(const float4*)&X[row * 256 + lane * 4];
  float s1 = x.x + x.y + x.z + x.w;
#pragma unroll
  for (int off = 1; off < 64; off <<= 1) s1 += __shfl_xor(s1, off);
  const float mean = s1 * (1.0f / 256.0f);
  const float dx = x.x - mean, dy = x.y - mean, dz = x.z - mean, dw = x.w - mean;
  float s2 = dx * dx + dy * dy + dz * dz + dw * dw;
#pragma unroll
  for (int off = 1; off < 64; off <<= 1) s2 += __shfl_xor(s2, off);
  const float rstd = rsqrtf(s2 * (1.0f / 256.0f) + 1e-5f);
  const int c0 = lane * 4;
  short4v y;
  y[0] = (short)f2bf(dx * rstd * g[c0] + bb[c0]);
  y[1] = (short)f2bf(dy * rstd * g[c0 + 1] + bb[c0 + 1]);
  y[2] = (short)f2bf(dz * rstd * g[c0 + 2] + bb[c0 + 2]);
  y[3] = (short)f2bf(dw * rstd * g[c0 + 3] + bb[c0 + 3]);
  *(short4v*)&out[row * 256 + c0] = y;
}

__global__ __launch_bounds__(256)
void ln2_kernel(const float* __restrict__ X, const float* __restrict__ g,
                const float* __restrict__ bb, float* __restrict__ out,
                const int* __restrict__ valid) {
  const int row = blockIdx.x * 4 + (threadIdx.x >> 6);
  const int lane = threadIdx.x & 63;
  const float4 x = *(const float4*)&X[row * 256 + lane * 4];
  float s1 = x.x + x.y + x.z + x.w;
#pragma unroll
  for (int off = 1; off < 64; off <<= 1) s1 += __shfl_xor(s1, off);
  const float mean = s1 * (1.0f / 256.0f);
  const float dx = x.x - mean, dy = x.y - mean, dz = x.z - mean, dw = x.w - mean;
  float s2 = dx * dx + dy * dy + dz * dz + dw * dw;
#pragma unroll
  for (int off = 1; off < 64; off <<= 1) s2 += __shfl_xor(s2, off);
  const float rstd = rsqrtf(s2 * (1.0f / 256.0f) + 1e-5f);
  const int c0 = lane * 4;
  const int bn = row >> 8, s = row & 255;
  const int b = bn >> 5, n = bn & 31;
  const float vmv = (valid[((b << 8) + s) * 32 + n] != 0) ? 1.0f : 0.0f;
  float4 y;
  y.x = (dx * rstd * g[c0] + bb[c0]) * vmv;
  y.y = (dy * rstd * g[c0 + 1] + bb[c0 + 1]) * vmv;
  y.z = (dz * rstd * g[c0 + 2] + bb[c0 + 2]) * vmv;
  y.w = (dw * rstd * g[c0 + 3] + bb[c0 + 3]) * vmv;
  *(float4*)&out[(((((b << 8) + s) << 5) + n) << 8) + c0] = y;
}

// ---------------------------------------------------------------------------
extern "C" void kernel_launch(void* const* d_in, const int* in_sizes, int n_in,
                              void* d_out, int out_size, void* d_ws, size_t ws_size,
                              hipStream_t stream) {
  const float* seq    = (const float*)d_in[0];
  const float* regs   = (const float*)d_in[1];
  const float* trs    = (const float*)d_in[2];
  const float* q_w    = (const float*)d_in[3];
  const float* q_b    = (const float*)d_in[4];
  const float* k_w    = (const float*)d_in[5];
  const float* k_b    = (const float*)d_in[6];
  const float* v_w    = (const float*)d_in[7];
  const float* v_b    = (const float*)d_in[8];
  const float* o_w    = (const float*)d_in[9];
  const float* o_b    = (const float*)d_in[10];
  const float* semb   = (const float*)d_in[11];
  const float* reg_w  = (const float*)d_in[12];
  const float* reg_b  = (const float*)d_in[13];
  const float* tr_w   = (const float*)d_in[14];
  const float* tr_b   = (const float*)d_in[15];
  const float* tq_w   = (const float*)d_in[16];
  const float* tq_b   = (const float*)d_in[17];
  const float* tk_w   = (const float*)d_in[18];
  const float* tk_b   = (const float*)d_in[19];
  const float* ff_w1  = (const float*)d_in[20];
  const float* ff_b1  = (const float*)d_in[21];
  const float* ff_w2  = (const float*)d_in[22];
  const float* ff_b2  = (const float*)d_in[23];
  const float* ln1_g  = (const float*)d_in[24];
  const float* ln1_b  = (const float*)d_in[25];
  const float* ln2_g  = (const float*)d_in[26];
  const float* ln2_b  = (const float*)d_in[27];
  const int*   valid  = (const int*)d_in[28];
  const int*   codes  = (const int*)d_in[29];

  float* f32ws = (float*)d_ws;
  float* ts    = f32ws;                 // 262144 f
  float* x1pre = f32ws + 262144;        // 8388608 f (reused as x2)
  unsigned short* bws = (unsigned short*)(f32ws + 262144 + 8388608);
  unsigned short* qb   = bws;                 // 8388608 (reused as x1b)
  unsigned short* kb   = bws + 8388608;       // 8388608 (reused as h1 lo)
  unsigned short* vb   = bws + 16777216;      // 8388608 (reused as h1 hi)
  unsigned short* ao   = bws + 25165824;      // 8388608
  unsigned short* tqb  = bws + 33554432;      // 262144
  unsigned short* tkb  = bws + 33816576;      // 262144
  unsigned short* wq   = bws + 34078720;      // 65536
  unsigned short* wk   = bws + 34144256;
  unsigned short* wv   = bws + 34209792;
  unsigned short* wo   = bws + 34275328;
  unsigned short* wtq  = bws + 34340864;
  unsigned short* wtk  = bws + 34406400;
  unsigned short* wff1 = bws + 34471936;      // 131072
  unsigned short* wff2 = bws + 34603008;      // 131072
  unsigned short* x1b  = qb;
  unsigned short* h1   = kb;                  // kb+vb contiguous 16777216
  float* x2 = x1pre;
  float* outp = (float*)d_out;

  // 1. time state
  ts_kernel<<<BS_, 256, 0, stream>>>(regs, trs, codes, semb, reg_w, reg_b,
                                     tr_w, tr_b, ts);
  // 2. weight conversion (bf16, transposed [N][K])
  cvtw_kernel<<<256, 256, 0, stream>>>(q_w, wq, 8, 256);
  cvtw_kernel<<<256, 256, 0, stream>>>(k_w, wk, 8, 256);
  cvtw_kernel<<<256, 256, 0, stream>>>(v_w, wv, 8, 256);
  cvtw_kernel<<<256, 256, 0, stream>>>(o_w, wo, 8, 256);
  cvtw_kernel<<<256, 256, 0, stream>>>(tq_w, wtq, 8, 256);
  cvtw_kernel<<<256, 256, 0, stream>>>(tk_w, wtk, 8, 256);
  cvtw_kernel<<<512, 256, 0, stream>>>(ff_w1, wff1, 9, 256);
  cvtw_kernel<<<512, 256, 0, stream>>>(ff_w2, wff2, 8, 512);
  // 3. temporal projections (0.25 folded into tq)
  mmb_kernel<0, 0, false, 256, 256, true><<<dim3(8, 2), 256, 0, stream>>>(
      ts, wtq, tq_b, nullptr, nullptr, nullptr, tqb, 0.25f);
  mmb_kernel<0, 0, false, 256, 256, true><<<dim3(8, 2), 256, 0, stream>>>(
      ts, wtk, tk_b, nullptr, nullptr, nullptr, tkb, 1.0f);
  // 4. q/k/v projections
  mmb_kernel<2, 0, false, 256, 256, true><<<dim3(256, 2), 256, 0, stream>>>(
      nullptr, wq, q_b, seq, ts, nullptr, qb, 1.0f);
  mmb_kernel<2, 0, false, 256, 256, true><<<dim3(256, 2), 256, 0, stream>>>(
      nullptr, wk, k_b, seq, ts, nullptr, kb, 1.0f);
  mmb_kernel<1, 0, false, 256, 256, true><<<dim3(256, 2), 256, 0, stream>>>(
      nullptr, wv, v_b, seq, nullptr, nullptr, vb, 1.0f);
  // 5. attention (v3: LDS P-bounce, no permlane)
  attn2_kernel<<<BN_ * NH_, 512, 0, stream>>>(qb, kb, vb, tqb, tkb, valid, ao);
  // 6. o-proj + seq residual -> x1pre (fp32); LN1 -> x1b (bf16)
  mmb_kernel<3, 1, false, 256, 256, false><<<dim3(256, 2), 256, 0, stream>>>(
      ao, wo, o_b, seq, nullptr, nullptr, x1pre, 1.0f);
  ln1_kernel<<<M_ / 4, 256, 0, stream>>>(x1pre, ln1_g, ln1_b, x1b);
  // 7. FF
  mmb_kernel<3, 0, true, 256, 512, true><<<dim3(256, 4), 256, 0, stream>>>(
      x1b, wff1, ff_b1, nullptr, nullptr, nullptr, h1, 1.0f);
  mmb_kernel<3, 2, false, 512, 256, false><<<dim3(256, 2), 256, 0, stream>>>(
      h1, wff2, ff_b2, nullptr, nullptr, x1b, x2, 1.0f);
  // 8. LN2 * valid -> output layout
  ln2_kernel<<<M_ / 4, 256, 0, stream>>>(x2, ln2_g, ln2_b, outp, valid);
}